// Round 1
// baseline (617.653 us; speedup 1.0000x reference)
//
#include <hip/hip_runtime.h>
#include <hip/hip_bf16.h>
#include <cstdint>
#include <cstddef>

typedef __bf16 bf16_t;
typedef __bf16 bf16x8 __attribute__((ext_vector_type(8)));
typedef float f32x4 __attribute__((ext_vector_type(4)));

#define NROWS 8192
#define DFEAT 1024
#define BK 32
#define LDK 40  // padded LDS leading dim (breaks pow2 bank stride, keeps 16B align)

__device__ __forceinline__ float fast_tanh(float x) {
  // exp-based tanh; saturates correctly for |x| large (expf->inf or 0)
  float e = __expf(2.0f * x);
  return 1.0f - 2.0f / (e + 1.0f);
}

__global__ __launch_bounds__(256) void split_kernel(const float* __restrict__ in,
                                                    bf16_t* __restrict__ hi,
                                                    bf16_t* __restrict__ lo, int n) {
  int i = blockIdx.x * 256 + threadIdx.x;
  if (i < n) {
    float v = in[i];
    bf16_t h = (bf16_t)v;
    hi[i] = h;
    lo[i] = (bf16_t)(v - (float)h);
  }
}

// Stage a 128 x 32 bf16 tile (rows row0.., cols k0..) from row-major g (leading dim lda)
__device__ __forceinline__ void stage_tile(const bf16_t* __restrict__ g, int lda,
                                           int row0, int k0,
                                           bf16_t (*lds)[LDK], int tid) {
#pragma unroll
  for (int t = 0; t < 2; ++t) {
    int c = tid + t * 256;       // 0..511
    int r = c >> 2;              // 0..127
    int kc = (c & 3) * 8;        // 0,8,16,24
    const uint4* src = (const uint4*)(g + (size_t)(row0 + r) * lda + k0 + kc);
    *(uint4*)(&lds[r][kc]) = *src;
  }
}

// h = x @ W^T + b, computed in split-bf16 (hi*hi + hi*lo + lo*hi), output bf16
__global__ __launch_bounds__(256) void gemm1_kernel(const bf16_t* __restrict__ xh,
                                                    const bf16_t* __restrict__ xl,
                                                    const bf16_t* __restrict__ Wh,
                                                    const bf16_t* __restrict__ Wl,
                                                    const float* __restrict__ bias,
                                                    bf16_t* __restrict__ hout) {
  __shared__ bf16_t lAh[128][LDK], lAl[128][LDK], lBh[128][LDK], lBl[128][LDK];
  const int tid = threadIdx.x;
  const int wave = tid >> 6, lane = tid & 63;
  const int wm = wave >> 1, wn = wave & 1;
  const int l15 = lane & 15, quad = lane >> 4;
  const int m0 = blockIdx.y * 128, n0 = blockIdx.x * 128;
  f32x4 acc[4][4] = {};
  for (int k0 = 0; k0 < DFEAT; k0 += BK) {
    __syncthreads();
    stage_tile(xh, DFEAT, m0, k0, lAh, tid);
    stage_tile(xl, DFEAT, m0, k0, lAl, tid);
    stage_tile(Wh, DFEAT, n0, k0, lBh, tid);
    stage_tile(Wl, DFEAT, n0, k0, lBl, tid);
    __syncthreads();
    bf16x8 ah[4], al[4], bh[4], bl[4];
#pragma unroll
    for (int f = 0; f < 4; ++f) {
      ah[f] = *(const bf16x8*)(&lAh[wm * 64 + f * 16 + l15][quad * 8]);
      al[f] = *(const bf16x8*)(&lAl[wm * 64 + f * 16 + l15][quad * 8]);
      bh[f] = *(const bf16x8*)(&lBh[wn * 64 + f * 16 + l15][quad * 8]);
      bl[f] = *(const bf16x8*)(&lBl[wn * 64 + f * 16 + l15][quad * 8]);
    }
#pragma unroll
    for (int i = 0; i < 4; ++i)
#pragma unroll
      for (int j = 0; j < 4; ++j) {
        acc[i][j] = __builtin_amdgcn_mfma_f32_16x16x32_bf16(ah[i], bh[j], acc[i][j], 0, 0, 0);
        acc[i][j] = __builtin_amdgcn_mfma_f32_16x16x32_bf16(ah[i], bl[j], acc[i][j], 0, 0, 0);
        acc[i][j] = __builtin_amdgcn_mfma_f32_16x16x32_bf16(al[i], bh[j], acc[i][j], 0, 0, 0);
      }
  }
#pragma unroll
  for (int i = 0; i < 4; ++i) {
    int rbase = m0 + wm * 64 + i * 16 + quad * 4;
#pragma unroll
    for (int j = 0; j < 4; ++j) {
      int col = n0 + wn * 64 + j * 16 + l15;
      float bv = bias[col];
#pragma unroll
      for (int r = 0; r < 4; ++r)
        hout[(size_t)(rbase + r) * DFEAT + col] = (bf16_t)(acc[i][j][r] + bv);
    }
  }
}

// hT[n][m] = h[m][n]
__global__ __launch_bounds__(256) void transpose_kernel(const bf16_t* __restrict__ in,
                                                        bf16_t* __restrict__ outT) {
  __shared__ bf16_t tile[64][65];
  int bm = blockIdx.y * 64;  // row block in h
  int bn = blockIdx.x * 64;  // col block in h
  int tid = threadIdx.x;
  int x = tid & 63, y0 = tid >> 6;
#pragma unroll
  for (int i = 0; i < 16; ++i) {
    int r = y0 * 16 + i;
    tile[r][x] = in[(size_t)(bm + r) * DFEAT + bn + x];
  }
  __syncthreads();
#pragma unroll
  for (int i = 0; i < 16; ++i) {
    int r = y0 * 16 + i;  // col in h
    outT[(size_t)(bn + r) * NROWS + bm + x] = tile[x][r];
  }
}

// P = exp(tanh(h @ h^T)), bf16
__global__ __launch_bounds__(256) void scores_kernel(const bf16_t* __restrict__ h,
                                                     bf16_t* __restrict__ P) {
  __shared__ bf16_t lA[128][LDK], lB[128][LDK];
  const int tid = threadIdx.x;
  const int wave = tid >> 6, lane = tid & 63;
  const int wm = wave >> 1, wn = wave & 1;
  const int l15 = lane & 15, quad = lane >> 4;
  const int m0 = blockIdx.y * 128, n0 = blockIdx.x * 128;
  f32x4 acc[4][4] = {};
  for (int k0 = 0; k0 < DFEAT; k0 += BK) {
    __syncthreads();
    stage_tile(h, DFEAT, m0, k0, lA, tid);
    stage_tile(h, DFEAT, n0, k0, lB, tid);
    __syncthreads();
    bf16x8 a[4], b[4];
#pragma unroll
    for (int f = 0; f < 4; ++f) {
      a[f] = *(const bf16x8*)(&lA[wm * 64 + f * 16 + l15][quad * 8]);
      b[f] = *(const bf16x8*)(&lB[wn * 64 + f * 16 + l15][quad * 8]);
    }
#pragma unroll
    for (int i = 0; i < 4; ++i)
#pragma unroll
      for (int j = 0; j < 4; ++j)
        acc[i][j] = __builtin_amdgcn_mfma_f32_16x16x32_bf16(a[i], b[j], acc[i][j], 0, 0, 0);
  }
#pragma unroll
  for (int i = 0; i < 4; ++i) {
    int rbase = m0 + wm * 64 + i * 16 + quad * 4;
#pragma unroll
    for (int j = 0; j < 4; ++j) {
      int col = n0 + wn * 64 + j * 16 + l15;
#pragma unroll
      for (int r = 0; r < 4; ++r) {
        float p = __expf(fast_tanh(acc[i][j][r]));
        P[(size_t)(rbase + r) * NROWS + col] = (bf16_t)p;
      }
    }
  }
}

__global__ __launch_bounds__(256) void rowsum_kernel(const bf16_t* __restrict__ P,
                                                     float* __restrict__ lsum) {
  int row = blockIdx.x, tid = threadIdx.x;
  const uint32_t* pr = (const uint32_t*)(P + (size_t)row * NROWS);
  float s = 0.f;
  for (int j = tid; j < NROWS / 2; j += 256) {
    union { uint32_t u; bf16_t b[2]; } cv;
    cv.u = pr[j];
    s += (float)cv.b[0] + (float)cv.b[1];
  }
#pragma unroll
  for (int off = 32; off > 0; off >>= 1) s += __shfl_down(s, off, 64);
  __shared__ float wsum[4];
  if ((tid & 63) == 0) wsum[tid >> 6] = s;
  __syncthreads();
  if (tid == 0) lsum[row] = (wsum[0] + wsum[1]) + (wsum[2] + wsum[3]);
}

// out = tanh((P @ h) / l)   using hT as B operand (row-major n,k)
__global__ __launch_bounds__(256) void pv_kernel(const bf16_t* __restrict__ P,
                                                 const bf16_t* __restrict__ hT,
                                                 const float* __restrict__ lsum,
                                                 float* __restrict__ out) {
  __shared__ bf16_t lA[128][LDK], lB[128][LDK];
  const int tid = threadIdx.x;
  const int wave = tid >> 6, lane = tid & 63;
  const int wm = wave >> 1, wn = wave & 1;
  const int l15 = lane & 15, quad = lane >> 4;
  const int m0 = blockIdx.y * 128, n0 = blockIdx.x * 128;
  f32x4 acc[4][4] = {};
  for (int k0 = 0; k0 < NROWS; k0 += BK) {
    __syncthreads();
    stage_tile(P, NROWS, m0, k0, lA, tid);
    stage_tile(hT, NROWS, n0, k0, lB, tid);
    __syncthreads();
    bf16x8 a[4], b[4];
#pragma unroll
    for (int f = 0; f < 4; ++f) {
      a[f] = *(const bf16x8*)(&lA[wm * 64 + f * 16 + l15][quad * 8]);
      b[f] = *(const bf16x8*)(&lB[wn * 64 + f * 16 + l15][quad * 8]);
    }
#pragma unroll
    for (int i = 0; i < 4; ++i)
#pragma unroll
      for (int j = 0; j < 4; ++j)
        acc[i][j] = __builtin_amdgcn_mfma_f32_16x16x32_bf16(a[i], b[j], acc[i][j], 0, 0, 0);
  }
#pragma unroll
  for (int i = 0; i < 4; ++i) {
    int rbase = m0 + wm * 64 + i * 16 + quad * 4;
#pragma unroll
    for (int r = 0; r < 4; ++r) {
      float rl = 1.0f / lsum[rbase + r];
#pragma unroll
      for (int j = 0; j < 4; ++j) {
        int col = n0 + wn * 64 + j * 16 + l15;
        out[(size_t)(rbase + r) * DFEAT + col] = fast_tanh(acc[i][j][r] * rl);
      }
    }
  }
}

extern "C" void kernel_launch(void* const* d_in, const int* in_sizes, int n_in,
                              void* d_out, int out_size, void* d_ws, size_t ws_size,
                              hipStream_t stream) {
  const float* x = (const float*)d_in[0];
  const float* W = (const float*)d_in[1];
  const float* bias = (const float*)d_in[2];
  float* out = (float*)d_out;

  // workspace layout (~196 MiB total)
  bf16_t* xh = (bf16_t*)d_ws;
  bf16_t* xl = xh + (size_t)NROWS * DFEAT;
  bf16_t* Wh = xl + (size_t)NROWS * DFEAT;
  bf16_t* Wl = Wh + (size_t)DFEAT * DFEAT;
  bf16_t* h  = Wl + (size_t)DFEAT * DFEAT;
  bf16_t* hT = h + (size_t)NROWS * DFEAT;
  float* lsum = (float*)(hT + (size_t)NROWS * DFEAT);
  bf16_t* P = (bf16_t*)(lsum + NROWS);

  split_kernel<<<(NROWS * DFEAT) / 256, 256, 0, stream>>>(x, xh, xl, NROWS * DFEAT);
  split_kernel<<<(DFEAT * DFEAT) / 256, 256, 0, stream>>>(W, Wh, Wl, DFEAT * DFEAT);
  gemm1_kernel<<<dim3(DFEAT / 128, NROWS / 128), 256, 0, stream>>>(xh, xl, Wh, Wl, bias, h);
  transpose_kernel<<<dim3(DFEAT / 64, NROWS / 64), 256, 0, stream>>>(h, hT);
  scores_kernel<<<dim3(NROWS / 128, NROWS / 128), 256, 0, stream>>>(h, P);
  rowsum_kernel<<<NROWS, 256, 0, stream>>>(P, lsum);
  pv_kernel<<<dim3(DFEAT / 128, NROWS / 128), 256, 0, stream>>>(P, hT, lsum, out);
}